// Round 1
// baseline (22101.649 us; speedup 1.0000x reference)
//
#include <hip/hip_runtime.h>
#include <hip/hip_bf16.h>

// Problem dims
constexpr int kH  = 2048;          // hidden
constexpr int kD  = 1024;          // input dim
constexpr int kT  = 4096;          // timesteps
constexpr int kTH = 3 * kH;        // 6144 gate rows
constexpr int kNB = 256;           // GRU grid blocks (both sequences)

// ---------------------------------------------------------------------------
// Round-7 post-mortem (17.4 ms GRU, 4.25 us/step): VALUBusy 19.9% => ~845 ns
// of compute/step; the other ~3.4 us is the 4-hop exchange chain:
//   h store -> vmcnt(0) drain -> flag store -> remote flag poll -> barrier B
//   -> 8 KB h reload -> barrier C.
// Round-8: fuse flag+data into ONE 8-byte word {tag=t+1 | f32 bits} stored
// with a single relaxed agent-scope 64-bit atomic. Consumers poll their own
// 4 words of the tagged h vector directly and unpack into LDS. This removes
// the producer vmcnt(0), the flag array, the dedicated poll wave, and
// barrier B: chain = store (one-way) + poll-detect (~1 hop each).
// Safety without producer drain: parity double-buffering gives a 2-step
// causal separation -- a word of buf[p] is overwritten at t+3 only after
// every block published t+2, which requires every block fully consumed t+1.
// Tag check is exact == (a protocol bug hangs visibly, never corrupts).
// Also: __launch_bounds__(512,1) (grid is 1 block/CU anyway) so the 192
// register-resident weights stay in arch VGPRs -- kills the 128/128
// arch/AGPR split whose accvgpr_read moves doubled matvec VALU issue.
// ---------------------------------------------------------------------------

__global__ void init_pub_kernel(unsigned long long* __restrict__ pub) {
    // zero 2 seq x 2 parity x kH tagged words = 8192
    pub[blockIdx.x * 1024 + threadIdx.x] = 0ull;
}

// fp32 tiled GEMM: xp[t][j] = sum_k x[t][k] * Wih[j][k] + bih[j]
__global__ __launch_bounds__(256) void gemm_xp_kernel(
    const float* __restrict__ x1, const float* __restrict__ x2,
    const float* __restrict__ Wih1, const float* __restrict__ Wih2,
    const float* __restrict__ bih1, const float* __restrict__ bih2,
    float* __restrict__ xp1, float* __restrict__ xp2) {
    const float* x  = blockIdx.z ? x2   : x1;
    const float* W  = blockIdx.z ? Wih2 : Wih1;
    const float* bi = blockIdx.z ? bih2 : bih1;
    float*       xp = blockIdx.z ? xp2  : xp1;

    __shared__ float As[16][68];
    __shared__ float Bs[16][68];

    const int tid  = threadIdx.x;
    const int tx   = tid & 15, ty = tid >> 4;
    const int lrow = tid >> 2;
    const int lk   = (tid & 3) * 4;
    const int m0   = blockIdx.y * 64;
    const int n0   = blockIdx.x * 64;

    float acc[4][4] = {};

    for (int k0 = 0; k0 < kD; k0 += 16) {
        float4 av = *(const float4*)(x + (size_t)(m0 + lrow) * kD + k0 + lk);
        float4 bv = *(const float4*)(W + (size_t)(n0 + lrow) * kD + k0 + lk);
        __syncthreads();
        As[lk + 0][lrow] = av.x; As[lk + 1][lrow] = av.y;
        As[lk + 2][lrow] = av.z; As[lk + 3][lrow] = av.w;
        Bs[lk + 0][lrow] = bv.x; Bs[lk + 1][lrow] = bv.y;
        Bs[lk + 2][lrow] = bv.z; Bs[lk + 3][lrow] = bv.w;
        __syncthreads();
#pragma unroll
        for (int kk = 0; kk < 16; ++kk) {
            float4 a = *(const float4*)&As[kk][ty * 4];
            float4 b = *(const float4*)&Bs[kk][tx * 4];
            float aa[4] = {a.x, a.y, a.z, a.w};
            float bb[4] = {b.x, b.y, b.z, b.w};
#pragma unroll
            for (int i = 0; i < 4; ++i)
#pragma unroll
                for (int j = 0; j < 4; ++j)
                    acc[i][j] = fmaf(aa[i], bb[j], acc[i][j]);
        }
    }

    float4 bb4 = *(const float4*)(bi + n0 + tx * 4);
    float bArr[4] = {bb4.x, bb4.y, bb4.z, bb4.w};
#pragma unroll
    for (int i = 0; i < 4; ++i) {
        float4 o;
        o.x = acc[i][0] + bArr[0];
        o.y = acc[i][1] + bArr[1];
        o.z = acc[i][2] + bArr[2];
        o.w = acc[i][3] + bArr[3];
        *(float4*)(xp + (size_t)(m0 + ty * 4 + i) * kTH + n0 + tx * 4) = o;
    }
}

// Persistent GRU, BOTH sequences. 256 blocks x 512 threads, 1 block/CU.
// Block b: sequence s=b>>7, hidden indices [i0,i0+16) -> 48 W_hh rows.
// 8 waves x 6 rows/wave; lane l owns cols {e*256+4l..+4}, w[6][32]=192
// regs/thread (arch VGPRs, launch_bounds(512,1)).
// Exchange: tagged-word publish. pub[s][parity][i] = (u64)(t+1)<<32 | bits(h).
// Every thread polls its own 4 words of pub[s][(t+1)&1] and unpacks to LDS.
__global__ __launch_bounds__(512, 1) void gru_pair_kernel(
    const float* __restrict__ xp1, const float* __restrict__ xp2,
    const float* __restrict__ Whh1, const float* __restrict__ Whh2,
    const float* __restrict__ bhh1, const float* __restrict__ bhh2,
    unsigned long long* __restrict__ pub,   // [2 seq][2 parity][kH]
    float* __restrict__ hfinal) {           // [2 seq][kH]
    const int tid  = threadIdx.x;
    const int lane = tid & 63;
    const int wv   = tid >> 6;          // 0..7
    const int b    = blockIdx.x;
    const int s    = b >> 7;
    const int lb   = b & 127;           // block index within sequence
    const int i0   = lb * 16;
    const float* xp  = s ? xp2  : xp1;
    const float* Whh = s ? Whh2 : Whh1;
    const float* bhh = s ? bhh2 : bhh1;
    unsigned long long* pubs = pub + (size_t)s * 2 * kH;

    __shared__ float h_s[kH];
    __shared__ float hp_s[48];
    __shared__ float xp_s[2][48];

    // one-time register-resident weight load:
    // lr = wv*6+p in [0,48), gate g=lr>>4, idx j=lr&15, row rg=g*kH+i0+j
    float w[6][32];
    float bias[6];
#pragma unroll
    for (int p = 0; p < 6; ++p) {
        const int lr = wv * 6 + p;
        const int g  = lr >> 4, j = lr & 15;
        const int rg = g * kH + i0 + j;
        bias[p] = bhh[rg];
        const float* wr = Whh + (size_t)rg * kH;
#pragma unroll
        for (int e = 0; e < 8; ++e) {
            float4 v = *(const float4*)(wr + e * 256 + lane * 4);
            w[p][e * 4 + 0] = v.x; w[p][e * 4 + 1] = v.y;
            w[p][e * 4 + 2] = v.z; w[p][e * 4 + 3] = v.w;
        }
    }
    {
        const int k = tid * 4;
        *(float4*)&h_s[k] = make_float4(0.f, 0.f, 0.f, 0.f);
    }
    // preload xp[0] into xp_s[0]
    if (tid < 48) {
        xp_s[0][tid] = xp[(size_t)(tid >> 4) * kH + i0 + (tid & 15)];
    }
    __syncthreads();

    for (int t = 0; t < kT; ++t) {
        // matvec: 6 rows/wave, weights in regs, h from LDS (conflict-free)
        float acc[6];
#pragma unroll
        for (int p = 0; p < 6; ++p) acc[p] = 0.f;
#pragma unroll
        for (int e = 0; e < 8; ++e) {
            const float4 hv = *(const float4*)&h_s[e * 256 + lane * 4];
#pragma unroll
            for (int p = 0; p < 6; ++p) {
                acc[p] = fmaf(w[p][e * 4 + 0], hv.x, acc[p]);
                acc[p] = fmaf(w[p][e * 4 + 1], hv.y, acc[p]);
                acc[p] = fmaf(w[p][e * 4 + 2], hv.z, acc[p]);
                acc[p] = fmaf(w[p][e * 4 + 3], hv.w, acc[p]);
            }
        }
#pragma unroll
        for (int p = 0; p < 6; ++p) {
            float a = acc[p];
#pragma unroll
            for (int off = 32; off; off >>= 1) a += __shfl_down(a, off, 64);
            if (lane == 0) hp_s[wv * 6 + p] = a + bias[p];
        }
        __syncthreads();   // (A) hp_s ready; h_s reads done

        unsigned long long* dst = pubs + (size_t)((t + 1) & 1) * kH;
        if (wv == 0) {
            // gates + tagged publish; tag travels WITH the data -> no vmcnt,
            // no flag store, no ordering hop.
            if (lane < 16) {
                const int i = i0 + lane;
                const float xr = xp_s[t & 1][lane];
                const float xz = xp_s[t & 1][16 + lane];
                const float xn = xp_s[t & 1][32 + lane];
                const float r = 1.f / (1.f + expf(-(xr + hp_s[lane])));
                const float z = 1.f / (1.f + expf(-(xz + hp_s[16 + lane])));
                const float n = tanhf(xn + r * hp_s[32 + lane]);
                const float hn = (1.f - z) * n + z * h_s[i];
                if (t == kT - 1) {
                    hfinal[s * kH + i] = hn;   // kernel boundary publishes
                } else {
                    const unsigned long long pk =
                        ((unsigned long long)(unsigned)(t + 1) << 32) |
                        (unsigned long long)__float_as_uint(hn);
                    __hip_atomic_store(&dst[i], pk, __ATOMIC_RELAXED,
                                       __HIP_MEMORY_SCOPE_AGENT);
                }
            }
        } else if (wv == 1) {
            // stage xp[t+1] during the poll window (hides HBM latency)
            if (t + 1 < kT && lane < 48) {
                xp_s[(t + 1) & 1][lane] =
                    xp[(size_t)(t + 1) * kTH + (size_t)(lane >> 4) * kH + i0 +
                       (lane & 15)];
            }
        }
        if (t + 1 == kT) break;

        // every thread polls its own 4 tagged words, unpacks into LDS
        {
            const unsigned tgt = (unsigned)(t + 1);
            const int base = tid * 4;
            unsigned long long v0, v1, v2, v3;
            for (;;) {
                v0 = __hip_atomic_load(&dst[base + 0], __ATOMIC_RELAXED,
                                       __HIP_MEMORY_SCOPE_AGENT);
                v1 = __hip_atomic_load(&dst[base + 1], __ATOMIC_RELAXED,
                                       __HIP_MEMORY_SCOPE_AGENT);
                v2 = __hip_atomic_load(&dst[base + 2], __ATOMIC_RELAXED,
                                       __HIP_MEMORY_SCOPE_AGENT);
                v3 = __hip_atomic_load(&dst[base + 3], __ATOMIC_RELAXED,
                                       __HIP_MEMORY_SCOPE_AGENT);
                if (((unsigned)(v0 >> 32) == tgt) &
                    ((unsigned)(v1 >> 32) == tgt) &
                    ((unsigned)(v2 >> 32) == tgt) &
                    ((unsigned)(v3 >> 32) == tgt))
                    break;
                __builtin_amdgcn_s_sleep(1);
            }
            float4 hv;
            hv.x = __uint_as_float((unsigned)v0);
            hv.y = __uint_as_float((unsigned)v1);
            hv.z = __uint_as_float((unsigned)v2);
            hv.w = __uint_as_float((unsigned)v3);
            *(float4*)&h_s[base] = hv;
        }
        __syncthreads();   // (C) h_s ready for next matvec
    }
}

// fc1(relu) -> fc2 -> log_softmax, single block of 256 threads
__global__ __launch_bounds__(256) void head_kernel(
    const float* __restrict__ h1, const float* __restrict__ h2,
    const float* __restrict__ fc1w, const float* __restrict__ fc1b,
    const float* __restrict__ fc2w, const float* __restrict__ fc2b,
    float* __restrict__ out) {
    __shared__ float cat[2 * kH];
    __shared__ float o1[256];
    __shared__ float logits[3];
    const int tid  = threadIdx.x;
    const int lane = tid & 63;
    const int wave = tid >> 6;

    for (int k = tid; k < kH; k += 256) {
        cat[k]      = h1[k];
        cat[kH + k] = h2[k];
    }
    __syncthreads();

    for (int r = wave; r < 256; r += 4) {
        const float* wr = fc1w + (size_t)r * (2 * kH);
        float acc = 0.f;
        for (int j = lane; j < 2 * kH; j += 64) acc = fmaf(wr[j], cat[j], acc);
#pragma unroll
        for (int off = 32; off; off >>= 1) acc += __shfl_down(acc, off, 64);
        if (lane == 0) o1[r] = fmaxf(acc + fc1b[r], 0.f);
    }
    __syncthreads();

    if (tid < 3) {
        float acc = fc2b[tid];
        const float* wr = fc2w + tid * 256;
        for (int j = 0; j < 256; ++j) acc = fmaf(wr[j], o1[j], acc);
        logits[tid] = acc;
    }
    __syncthreads();

    if (tid == 0) {
        float m = fmaxf(logits[0], fmaxf(logits[1], logits[2]));
        float s = expf(logits[0] - m) + expf(logits[1] - m) + expf(logits[2] - m);
        float ls = logf(s);
        out[0] = logits[0] - m - ls;
        out[1] = logits[1] - m - ls;
        out[2] = logits[2] - m - ls;
    }
}

extern "C" void kernel_launch(void* const* d_in, const int* in_sizes, int n_in,
                              void* d_out, int out_size, void* d_ws,
                              size_t ws_size, hipStream_t stream) {
    const float* x1   = (const float*)d_in[0];
    const float* x2   = (const float*)d_in[1];
    const float* Wih1 = (const float*)d_in[2];
    const float* Whh1 = (const float*)d_in[3];
    const float* bih1 = (const float*)d_in[4];
    const float* bhh1 = (const float*)d_in[5];
    const float* Wih2 = (const float*)d_in[6];
    const float* Whh2 = (const float*)d_in[7];
    const float* bih2 = (const float*)d_in[8];
    const float* bhh2 = (const float*)d_in[9];
    const float* fc1w = (const float*)d_in[10];
    const float* fc1b = (const float*)d_in[11];
    const float* fc2w = (const float*)d_in[12];
    const float* fc2b = (const float*)d_in[13];
    float* out = (float*)d_out;

    char* ws = (char*)d_ws;
    float* xp1 = (float*)ws;
    float* xp2 = xp1 + (size_t)kT * kTH;
    unsigned long long* pub = (unsigned long long*)(xp2 + (size_t)kT * kTH);
    float* hfinal = (float*)(pub + 4 * kH);   // 2 seq x kH

    init_pub_kernel<<<8, 1024, 0, stream>>>(pub);

    gemm_xp_kernel<<<dim3(kTH / 64, kT / 64, 2), 256, 0, stream>>>(
        x1, x2, Wih1, Wih2, bih1, bih2, xp1, xp2);

    gru_pair_kernel<<<dim3(kNB), dim3(512), 0, stream>>>(
        xp1, xp2, Whh1, Whh2, bhh1, bhh2, pub, hfinal);

    head_kernel<<<1, 256, 0, stream>>>(hfinal, hfinal + kH, fc1w, fc1b, fc2w,
                                       fc2b, out);
}